// Round 2
// baseline (376.104 us; speedup 1.0000x reference)
//
#include <hip/hip_runtime.h>
#include <hip/hip_bf16.h>

#define B_ 2
#define S_ 2048
#define D_ 1024
#define H_ 16
#define HD_ 64

typedef __attribute__((ext_vector_type(8))) short bf16x8;
typedef __attribute__((ext_vector_type(4))) short short4v;
typedef __attribute__((ext_vector_type(4))) float floatx4;

static __device__ __forceinline__ float bf2f(short u) {
  union { float f; unsigned int i; } c;
  c.i = ((unsigned int)(unsigned short)u) << 16;
  return c.f;
}
static __device__ __forceinline__ short f2bf(float f) {
  union { float f; unsigned int i; } c; c.f = f;
  unsigned int r = c.i + 0x7FFFu + ((c.i >> 16) & 1u);
  return (short)(r >> 16);
}

static __device__ __forceinline__ void gld_lds16(const void* g, void* l) {
  __builtin_amdgcn_global_load_lds(
      (const __attribute__((address_space(1))) unsigned int*)g,
      (__attribute__((address_space(3))) unsigned int*)l, 16, 0, 0);
}

// ---------------- fp32 -> bf16 convert (hidden_states) ----------------
__global__ __launch_bounds__(256)
void cvt_hs(const float4* __restrict__ in, short4v* __restrict__ out) {
  const int i = blockIdx.x * 256 + threadIdx.x;
  const float4 v = in[i];
  short4v o;
  o[0] = f2bf(v.x); o[1] = f2bf(v.y); o[2] = f2bf(v.z); o[3] = f2bf(v.w);
  out[i] = o;
}

// ---------------- transpose 4 DxD fp32 weights -> bf16 W^T ----------------
__global__ __launch_bounds__(256)
void transpose4(const float* __restrict__ w0, const float* __restrict__ w1,
                const float* __restrict__ w2, const float* __restrict__ w3,
                short* __restrict__ out) {
  __shared__ short t[64][65];
  const int z = blockIdx.z;
  const float* src = z == 0 ? w0 : z == 1 ? w1 : z == 2 ? w2 : w3;
  short* dst = out + (size_t)z * D_ * D_;
  const int tx = threadIdx.x & 63, ty = threadIdx.x >> 6;
  const int r0 = blockIdx.y * 64, c0 = blockIdx.x * 64;
  for (int r = ty; r < 64; r += 4)
    t[r][tx] = f2bf(src[(size_t)(r0 + r) * D_ + c0 + tx]);
  __syncthreads();
  for (int r = ty; r < 64; r += 4)
    dst[(size_t)(c0 + r) * D_ + r0 + tx] = t[tx][r];
}

// ---------------- fused QKV GEMM: Xb[4096,1024] @ {Wq,Wk,Wv}^T + bias ----------------
// WT holds q_w^T, k_w^T, v_w^T consecutively ([n][k], k-contiguous, bf16).
// Writes Q,K as [B,H,S,HD]; V transposed as [B,H,HD,S] (all bf16).
__global__ __launch_bounds__(256, 2)
void gemm_qkv(const short* __restrict__ X, const short* __restrict__ WT,
              const float* __restrict__ qb, const float* __restrict__ kb,
              const float* __restrict__ vb,
              short* __restrict__ Qo, short* __restrict__ Ko,
              short* __restrict__ Vt) {
  __shared__ __align__(16) short As[128 * 32];
  __shared__ __align__(16) short Bs[128 * 32];
  const int tid = threadIdx.x;
  const int wave = tid >> 6, lane = tid & 63;
  const int col = lane & 15, quad = lane >> 4;
  const int m0 = blockIdx.x * 128;
  const int nt = blockIdx.y;
  const int widx = nt >> 3;           // 0=Q 1=K 2=V (8 n-tiles per weight)
  const int n1 = (nt & 7) * 128;      // n offset within weight
  const short* Bsrc = WT + (size_t)widx * D_ * D_ + (size_t)n1 * D_;
  const int wrow = (wave & 1) * 64;
  const int wcol = (wave >> 1) * 64;

  floatx4 acc[4][4];
#pragma unroll
  for (int i = 0; i < 4; i++)
#pragma unroll
    for (int j = 0; j < 4; j++) acc[i][j] = floatx4{0.f, 0.f, 0.f, 0.f};

  const int srow = tid >> 2;
  const int skcol = (tid & 3) * 8;
  const short* ga = X + (size_t)(m0 + srow) * D_ + skcol;
  const short* gb = Bsrc + (size_t)srow * D_ + skcol;
  short* la = As + tid * 8;
  short* lb = Bs + tid * 8;

  for (int k0 = 0; k0 < D_; k0 += 32) {
    gld_lds16(ga, la);
    gld_lds16(ga + 64 * D_, la + 2048);
    gld_lds16(gb, lb);
    gld_lds16(gb + 64 * D_, lb + 2048);
    ga += 32; gb += 32;
    __syncthreads();
    bf16x8 af[4], bfr[4];
#pragma unroll
    for (int i = 0; i < 4; i++)
      af[i] = *(const bf16x8*)(As + (wrow + i * 16 + col) * 32 + quad * 8);
#pragma unroll
    for (int j = 0; j < 4; j++)
      bfr[j] = *(const bf16x8*)(Bs + (wcol + j * 16 + col) * 32 + quad * 8);
#pragma unroll
    for (int i = 0; i < 4; i++)
#pragma unroll
      for (int j = 0; j < 4; j++)
        acc[i][j] = __builtin_amdgcn_mfma_f32_16x16x32_bf16(af[i], bfr[j],
                                                            acc[i][j], 0, 0, 0);
    __syncthreads();
  }

  const float* bias = widx == 0 ? qb : widx == 1 ? kb : vb;
  float bv[4];
#pragma unroll
  for (int j = 0; j < 4; j++) bv[j] = bias[n1 + wcol + j * 16 + col];

  const int b = m0 >> 11;
  if (widx < 2) {
    short* dst = widx == 0 ? Qo : Ko;
#pragma unroll
    for (int i = 0; i < 4; i++) {
      const int s = (m0 + wrow + i * 16 + quad * 4) & (S_ - 1);
#pragma unroll
      for (int j = 0; j < 4; j++) {
        const int nl = n1 + wcol + j * 16 + col;
        const int h = nl >> 6, hd = nl & 63;
        const size_t base = ((size_t)(b * H_ + h) * S_ + s) * HD_ + hd;
#pragma unroll
        for (int r = 0; r < 4; r++)
          dst[base + (size_t)r * HD_] = f2bf(acc[i][j][r] + bv[j]);
      }
    }
  } else {
#pragma unroll
    for (int i = 0; i < 4; i++) {
      const int s = (m0 + wrow + i * 16 + quad * 4) & (S_ - 1);
#pragma unroll
      for (int j = 0; j < 4; j++) {
        const int nl = n1 + wcol + j * 16 + col;
        const int h = nl >> 6, hd = nl & 63;
        short4v pk;
#pragma unroll
        for (int r = 0; r < 4; r++) pk[r] = f2bf(acc[i][j][r] + bv[j]);
        *(short4v*)(Vt + ((size_t)(b * H_ + h) * HD_ + hd) * S_ + s) = pk;
      }
    }
  }
}

// ---------------- flash attention ----------------
// grid (S/64, H, B), 256 threads = 4 waves, wave handles 16 q-rows.
// K/V fragments loaded directly from global (cache-served); no block barriers.
__global__ __launch_bounds__(256, 2)
void attn(const short* __restrict__ Q, const short* __restrict__ K,
          const short* __restrict__ Vt, const float* __restrict__ mask,
          short* __restrict__ ctx) {
  __shared__ __align__(16) short P[4][16][72];  // per-wave strip, stride 72
  const int tid = threadIdx.x, wave = tid >> 6, lane = tid & 63;
  const int col = lane & 15, quad = lane >> 4;
  const int qt = blockIdx.x, h = blockIdx.y, b = blockIdx.z;
  const short* Qh = Q + (size_t)(b * H_ + h) * S_ * HD_;
  const short* Kh = K + (size_t)(b * H_ + h) * S_ * HD_;
  const short* Vh = Vt + (size_t)(b * H_ + h) * HD_ * S_;
  const float* mk = mask + (size_t)b * S_;
  const int q0 = qt * 64 + wave * 16;

  const bf16x8 qf0 = *(const bf16x8*)(Qh + (size_t)(q0 + col) * HD_ + quad * 8);
  const bf16x8 qf1 = *(const bf16x8*)(Qh + (size_t)(q0 + col) * HD_ + 32 + quad * 8);

  floatx4 acc[4];
#pragma unroll
  for (int d = 0; d < 4; d++) acc[d] = floatx4{0.f, 0.f, 0.f, 0.f};
  float mrun[4], lrun[4];
#pragma unroll
  for (int r = 0; r < 4; r++) { mrun[r] = -1e30f; lrun[r] = 0.f; }

  for (int kt = 0; kt < S_; kt += 64) {
    floatx4 sv[4];
#pragma unroll
    for (int t = 0; t < 4; t++) {
      const short* kp = Kh + (size_t)(kt + t * 16 + col) * HD_;
      const bf16x8 kf0 = *(const bf16x8*)(kp + quad * 8);
      const bf16x8 kf1 = *(const bf16x8*)(kp + 32 + quad * 8);
      floatx4 z = floatx4{0.f, 0.f, 0.f, 0.f};
      z = __builtin_amdgcn_mfma_f32_16x16x32_bf16(qf0, kf0, z, 0, 0, 0);
      z = __builtin_amdgcn_mfma_f32_16x16x32_bf16(qf1, kf1, z, 0, 0, 0);
      const float mterm = (1.0f - mk[kt + t * 16 + col]) * -10000.0f;
#pragma unroll
      for (int r = 0; r < 4; r++) sv[t][r] = z[r] * 0.125f + mterm;
    }
    float mnew[4], alpha[4], rs[4];
#pragma unroll
    for (int r = 0; r < 4; r++) {
      float v = fmaxf(fmaxf(sv[0][r], sv[1][r]), fmaxf(sv[2][r], sv[3][r]));
      v = fmaxf(v, __shfl_xor(v, 1));
      v = fmaxf(v, __shfl_xor(v, 2));
      v = fmaxf(v, __shfl_xor(v, 4));
      v = fmaxf(v, __shfl_xor(v, 8));
      mnew[r] = fmaxf(mrun[r], v);
      alpha[r] = __expf(mrun[r] - mnew[r]);
      mrun[r] = mnew[r];
      rs[r] = 0.f;
    }
#pragma unroll
    for (int t = 0; t < 4; t++)
#pragma unroll
      for (int r = 0; r < 4; r++) {
        const float p = __expf(sv[t][r] - mnew[r]);
        sv[t][r] = p;
        rs[r] += p;
      }
#pragma unroll
    for (int r = 0; r < 4; r++) {
      float v = rs[r];
      v += __shfl_xor(v, 1); v += __shfl_xor(v, 2);
      v += __shfl_xor(v, 4); v += __shfl_xor(v, 8);
      lrun[r] = lrun[r] * alpha[r] + v;
    }
#pragma unroll
    for (int d = 0; d < 4; d++)
#pragma unroll
      for (int r = 0; r < 4; r++) acc[d][r] *= alpha[r];

    // C-layout P -> LDS -> A-layout fragments (bf16), per-wave strip
#pragma unroll
    for (int t = 0; t < 4; t++)
#pragma unroll
      for (int r = 0; r < 4; r++)
        P[wave][quad * 4 + r][t * 16 + col] = f2bf(sv[t][r]);

    asm volatile("s_waitcnt lgkmcnt(0)" ::: "memory");

    bf16x8 pf[2];
#pragma unroll
    for (int kk = 0; kk < 2; kk++) {
      const short4v p0 = *(const short4v*)&P[wave][col][kk * 32 + quad * 8];
      const short4v p1 = *(const short4v*)&P[wave][col][kk * 32 + quad * 8 + 4];
      bf16x8 pv;
      pv[0] = p0[0]; pv[1] = p0[1]; pv[2] = p0[2]; pv[3] = p0[3];
      pv[4] = p1[0]; pv[5] = p1[1]; pv[6] = p1[2]; pv[7] = p1[3];
      pf[kk] = pv;
    }
#pragma unroll
    for (int d = 0; d < 4; d++) {
      const short* vp = Vh + (size_t)(d * 16 + col) * S_ + kt;
      const bf16x8 vf0 = *(const bf16x8*)(vp + quad * 8);
      const bf16x8 vf1 = *(const bf16x8*)(vp + 32 + quad * 8);
      acc[d] = __builtin_amdgcn_mfma_f32_16x16x32_bf16(pf[0], vf0, acc[d], 0, 0, 0);
      acc[d] = __builtin_amdgcn_mfma_f32_16x16x32_bf16(pf[1], vf1, acc[d], 0, 0, 0);
    }
  }

#pragma unroll
  for (int r = 0; r < 4; r++) lrun[r] = 1.0f / lrun[r];
#pragma unroll
  for (int d = 0; d < 4; d++)
#pragma unroll
    for (int r = 0; r < 4; r++)
      ctx[((size_t)b * S_ + q0 + quad * 4 + r) * D_ + h * HD_ + d * 16 + col] =
          f2bf(acc[d][r] * lrun[r]);
}

// ---------------- output projection: ctx @ o_w + o_b (fp32 out) ----------------
__global__ __launch_bounds__(256, 2)
void gemm_out(const short* __restrict__ X, const short* __restrict__ WT,
              const float* __restrict__ ob, float* __restrict__ out) {
  __shared__ __align__(16) short As[128 * 32];
  __shared__ __align__(16) short Bs[128 * 32];
  const int tid = threadIdx.x;
  const int wave = tid >> 6, lane = tid & 63;
  const int col = lane & 15, quad = lane >> 4;
  const int m0 = blockIdx.x * 128;
  const int n0 = blockIdx.y * 128;
  const short* Bsrc = WT + (size_t)n0 * D_;
  const int wrow = (wave & 1) * 64;
  const int wcol = (wave >> 1) * 64;

  floatx4 acc[4][4];
#pragma unroll
  for (int i = 0; i < 4; i++)
#pragma unroll
    for (int j = 0; j < 4; j++) acc[i][j] = floatx4{0.f, 0.f, 0.f, 0.f};

  const int srow = tid >> 2;
  const int skcol = (tid & 3) * 8;
  const short* ga = X + (size_t)(m0 + srow) * D_ + skcol;
  const short* gb = Bsrc + (size_t)srow * D_ + skcol;
  short* la = As + tid * 8;
  short* lb = Bs + tid * 8;

  for (int k0 = 0; k0 < D_; k0 += 32) {
    gld_lds16(ga, la);
    gld_lds16(ga + 64 * D_, la + 2048);
    gld_lds16(gb, lb);
    gld_lds16(gb + 64 * D_, lb + 2048);
    ga += 32; gb += 32;
    __syncthreads();
    bf16x8 af[4], bfr[4];
#pragma unroll
    for (int i = 0; i < 4; i++)
      af[i] = *(const bf16x8*)(As + (wrow + i * 16 + col) * 32 + quad * 8);
#pragma unroll
    for (int j = 0; j < 4; j++)
      bfr[j] = *(const bf16x8*)(Bs + (wcol + j * 16 + col) * 32 + quad * 8);
#pragma unroll
    for (int i = 0; i < 4; i++)
#pragma unroll
      for (int j = 0; j < 4; j++)
        acc[i][j] = __builtin_amdgcn_mfma_f32_16x16x32_bf16(af[i], bfr[j],
                                                            acc[i][j], 0, 0, 0);
    __syncthreads();
  }

  float bv[4];
#pragma unroll
  for (int j = 0; j < 4; j++) bv[j] = ob[n0 + wcol + j * 16 + col];

#pragma unroll
  for (int i = 0; i < 4; i++) {
    const int m = m0 + wrow + i * 16 + quad * 4;
#pragma unroll
    for (int j = 0; j < 4; j++) {
      const int n = n0 + wcol + j * 16 + col;
#pragma unroll
      for (int r = 0; r < 4; r++)
        out[(size_t)(m + r) * D_ + n] = acc[i][j][r] + bv[j];
    }
  }
}

extern "C" void kernel_launch(void* const* d_in, const int* in_sizes, int n_in,
                              void* d_out, int out_size, void* d_ws, size_t ws_size,
                              hipStream_t stream) {
  (void)in_sizes; (void)n_in; (void)out_size; (void)ws_size;
  const float* hs  = (const float*)d_in[0];
  const float* msk = (const float*)d_in[1];
  const float* qw  = (const float*)d_in[2];
  const float* qb  = (const float*)d_in[3];
  const float* kw  = (const float*)d_in[4];
  const float* kb  = (const float*)d_in[5];
  const float* vw  = (const float*)d_in[6];
  const float* vb  = (const float*)d_in[7];
  const float* ow  = (const float*)d_in[8];
  const float* ob  = (const float*)d_in[9];
  float* out = (float*)d_out;
  char* ws = (char*)d_ws;

  short* Xb  = (short*)(ws);                    // bf16 hs [4096,1024] (8 MB); reused as Ctx
  short* WT  = (short*)(ws + (8ull  << 20));    // 4 x 1024x1024 bf16 (8 MB)
  short* Qp  = (short*)(ws + (16ull << 20));    // [B,H,S,HD] (8 MB)
  short* Kp  = (short*)(ws + (24ull << 20));    // [B,H,S,HD] (8 MB)
  short* Vtp = (short*)(ws + (32ull << 20));    // [B,H,HD,S] (8 MB)
  short* Ctx = Xb;                              // [B,S,D] bf16 (overlays Xb)

  cvt_hs<<<dim3(4096), 256, 0, stream>>>((const float4*)hs, (short4v*)Xb);
  transpose4<<<dim3(16, 16, 4), 256, 0, stream>>>(qw, kw, vw, ow, WT);
  gemm_qkv<<<dim3(32, 24), 256, 0, stream>>>(Xb, WT, qb, kb, vb, Qp, Kp, Vtp);
  attn<<<dim3(32, 16, 2), 256, 0, stream>>>(Qp, Kp, Vtp, msk, Ctx);
  gemm_out<<<dim3(32, 8), 256, 0, stream>>>(Ctx, WT + 3ull * D_ * D_, ob, out);
}

// Round 3
// 255.648 us; speedup vs baseline: 1.4712x; 1.4712x over previous
//
#include <hip/hip_runtime.h>
#include <hip/hip_bf16.h>

#define B_ 2
#define S_ 2048
#define D_ 1024
#define H_ 16
#define HD_ 64

typedef __attribute__((ext_vector_type(8))) short bf16x8;
typedef __attribute__((ext_vector_type(4))) short short4v;
typedef __attribute__((ext_vector_type(4))) float floatx4;

static __device__ __forceinline__ float bf2f(short u) {
  union { float f; unsigned int i; } c;
  c.i = ((unsigned int)(unsigned short)u) << 16;
  return c.f;
}
static __device__ __forceinline__ short f2bf(float f) {
  union { float f; unsigned int i; } c; c.f = f;
  unsigned int r = c.i + 0x7FFFu + ((c.i >> 16) & 1u);
  return (short)(r >> 16);
}

static __device__ __forceinline__ void gld_lds16(const void* g, void* l) {
  __builtin_amdgcn_global_load_lds(
      (const __attribute__((address_space(1))) unsigned int*)g,
      (__attribute__((address_space(3))) unsigned int*)l, 16, 0, 0);
}

// ---------------- fp32 -> bf16 convert (hidden_states) ----------------
__global__ __launch_bounds__(256)
void cvt_hs(const float4* __restrict__ in, short4v* __restrict__ out) {
  const int i = blockIdx.x * 256 + threadIdx.x;
  const float4 v = in[i];
  short4v o;
  o[0] = f2bf(v.x); o[1] = f2bf(v.y); o[2] = f2bf(v.z); o[3] = f2bf(v.w);
  out[i] = o;
}

// ---------------- transpose 4 DxD fp32 weights -> bf16 W^T ----------------
__global__ __launch_bounds__(256)
void transpose4(const float* __restrict__ w0, const float* __restrict__ w1,
                const float* __restrict__ w2, const float* __restrict__ w3,
                short* __restrict__ out) {
  __shared__ short t[64][65];
  const int z = blockIdx.z;
  const float* src = z == 0 ? w0 : z == 1 ? w1 : z == 2 ? w2 : w3;
  short* dst = out + (size_t)z * D_ * D_;
  const int tx = threadIdx.x & 63, ty = threadIdx.x >> 6;
  const int r0 = blockIdx.y * 64, c0 = blockIdx.x * 64;
  for (int r = ty; r < 64; r += 4)
    t[r][tx] = f2bf(src[(size_t)(r0 + r) * D_ + c0 + tx]);
  __syncthreads();
  for (int r = ty; r < 64; r += 4)
    dst[(size_t)(c0 + r) * D_ + r0 + tx] = t[tx][r];
}

// ---------------- fused QKV GEMM: Xb[4096,1024] @ {Wq,Wk,Wv}^T + bias ----------------
__global__ __launch_bounds__(256, 2)
void gemm_qkv(const short* __restrict__ X, const short* __restrict__ WT,
              const float* __restrict__ qb, const float* __restrict__ kb,
              const float* __restrict__ vb,
              short* __restrict__ Qo, short* __restrict__ Ko,
              short* __restrict__ Vt) {
  __shared__ __align__(16) short As[128 * 32];
  __shared__ __align__(16) short Bs[128 * 32];
  const int tid = threadIdx.x;
  const int wave = tid >> 6, lane = tid & 63;
  const int col = lane & 15, quad = lane >> 4;
  const int m0 = blockIdx.x * 128;
  const int nt = blockIdx.y;
  const int widx = nt >> 3;           // 0=Q 1=K 2=V (8 n-tiles per weight)
  const int n1 = (nt & 7) * 128;      // n offset within weight
  const short* Bsrc = WT + (size_t)widx * D_ * D_ + (size_t)n1 * D_;
  const int wrow = (wave & 1) * 64;
  const int wcol = (wave >> 1) * 64;

  floatx4 acc[4][4];
#pragma unroll
  for (int i = 0; i < 4; i++)
#pragma unroll
    for (int j = 0; j < 4; j++) acc[i][j] = floatx4{0.f, 0.f, 0.f, 0.f};

  const int srow = tid >> 2;
  const int skcol = (tid & 3) * 8;
  const short* ga = X + (size_t)(m0 + srow) * D_ + skcol;
  const short* gb = Bsrc + (size_t)srow * D_ + skcol;
  short* la = As + tid * 8;
  short* lb = Bs + tid * 8;

  for (int k0 = 0; k0 < D_; k0 += 32) {
    gld_lds16(ga, la);
    gld_lds16(ga + 64 * D_, la + 2048);
    gld_lds16(gb, lb);
    gld_lds16(gb + 64 * D_, lb + 2048);
    ga += 32; gb += 32;
    __syncthreads();
    bf16x8 af[4], bfr[4];
#pragma unroll
    for (int i = 0; i < 4; i++)
      af[i] = *(const bf16x8*)(As + (wrow + i * 16 + col) * 32 + quad * 8);
#pragma unroll
    for (int j = 0; j < 4; j++)
      bfr[j] = *(const bf16x8*)(Bs + (wcol + j * 16 + col) * 32 + quad * 8);
#pragma unroll
    for (int i = 0; i < 4; i++)
#pragma unroll
      for (int j = 0; j < 4; j++)
        acc[i][j] = __builtin_amdgcn_mfma_f32_16x16x32_bf16(af[i], bfr[j],
                                                            acc[i][j], 0, 0, 0);
    __syncthreads();
  }

  const float* bias = widx == 0 ? qb : widx == 1 ? kb : vb;
  float bv[4];
#pragma unroll
  for (int j = 0; j < 4; j++) bv[j] = bias[n1 + wcol + j * 16 + col];

  const int b = m0 >> 11;
  if (widx < 2) {
    short* dst = widx == 0 ? Qo : Ko;
#pragma unroll
    for (int i = 0; i < 4; i++) {
      const int s = (m0 + wrow + i * 16 + quad * 4) & (S_ - 1);
#pragma unroll
      for (int j = 0; j < 4; j++) {
        const int nl = n1 + wcol + j * 16 + col;
        const int h = nl >> 6, hd = nl & 63;
        const size_t base = ((size_t)(b * H_ + h) * S_ + s) * HD_ + hd;
#pragma unroll
        for (int r = 0; r < 4; r++)
          dst[base + (size_t)r * HD_] = f2bf(acc[i][j][r] + bv[j]);
      }
    }
  } else {
#pragma unroll
    for (int i = 0; i < 4; i++) {
      const int s = (m0 + wrow + i * 16 + quad * 4) & (S_ - 1);
#pragma unroll
      for (int j = 0; j < 4; j++) {
        const int nl = n1 + wcol + j * 16 + col;
        const int h = nl >> 6, hd = nl & 63;
        short4v pk;
#pragma unroll
        for (int r = 0; r < 4; r++) pk[r] = f2bf(acc[i][j][r] + bv[j]);
        *(short4v*)(Vt + ((size_t)(b * H_ + h) * HD_ + hd) * S_ + s) = pk;
      }
    }
  }
}

// ---------------- flash attention (LDS-staged K/V, XOR-swizzled) ----------------
// grid (S/64, H, B), 256 threads = 4 waves, wave handles 16 q-rows.
// K-tile (64 keys x 64 hd) and V-tile (64 hd x 64 keys) staged via
// global_load_lds width-16; chunk c of row r stored at slot c^(r&7) so
// fragment b128 reads spread across bank groups.
__global__ __launch_bounds__(256, 4)
void attn(const short* __restrict__ Q, const short* __restrict__ K,
          const short* __restrict__ Vt, const float* __restrict__ mask,
          short* __restrict__ ctx) {
  __shared__ __align__(16) short Ks[64 * 64];   // 8 KB
  __shared__ __align__(16) short Vs[64 * 64];   // 8 KB
  __shared__ __align__(16) short P[4][16][72];  // per-wave strips, 9 KB
  const int tid = threadIdx.x, wave = tid >> 6, lane = tid & 63;
  const int col = lane & 15, quad = lane >> 4;
  const int qt = blockIdx.x, h = blockIdx.y, b = blockIdx.z;
  const short* Qh = Q + (size_t)(b * H_ + h) * S_ * HD_;
  const short* Kh = K + (size_t)(b * H_ + h) * S_ * HD_;
  const short* Vh = Vt + (size_t)(b * H_ + h) * HD_ * S_;
  const float* mk = mask + (size_t)b * S_;
  const int q0 = qt * 64 + wave * 16;

  // staging chunk mapping: chunk i (i = 0..511) = row i>>3, slot i&7;
  // source chunk col = slot ^ (row&7)
  const int r1 = tid >> 3, c1 = (tid & 7) ^ (r1 & 7);
  const int r2 = r1 + 32,  c2 = (tid & 7) ^ (r2 & 7);

  const bf16x8 qf0 = *(const bf16x8*)(Qh + (size_t)(q0 + col) * HD_ + quad * 8);
  const bf16x8 qf1 = *(const bf16x8*)(Qh + (size_t)(q0 + col) * HD_ + 32 + quad * 8);

  floatx4 acc[4];
#pragma unroll
  for (int d = 0; d < 4; d++) acc[d] = floatx4{0.f, 0.f, 0.f, 0.f};
  float mrun[4], lrun[4];
#pragma unroll
  for (int r = 0; r < 4; r++) { mrun[r] = -1e30f; lrun[r] = 0.f; }

  const int swz = quad ^ (col & 7);  // fragment slot for both K and V reads

  for (int kt = 0; kt < S_; kt += 64) {
    __syncthreads();  // previous iteration's LDS reads done
    // stage K rows kt..kt+63 (64 hd each) and V rows hd 0..63 (keys kt..kt+63)
    gld_lds16(Kh + (size_t)(kt + r1) * HD_ + c1 * 8, Ks + tid * 8);
    gld_lds16(Kh + (size_t)(kt + r2) * HD_ + c2 * 8, Ks + (tid + 256) * 8);
    gld_lds16(Vh + (size_t)r1 * S_ + kt + c1 * 8, Vs + tid * 8);
    gld_lds16(Vh + (size_t)r2 * S_ + kt + c2 * 8, Vs + (tid + 256) * 8);
    __syncthreads();  // staging complete

    floatx4 sv[4];
#pragma unroll
    for (int t = 0; t < 4; t++) {
      const short* kp = Ks + (t * 16 + col) * 64;
      const bf16x8 kf0 = *(const bf16x8*)(kp + swz * 8);
      const bf16x8 kf1 = *(const bf16x8*)(kp + (swz ^ 4) * 8);
      floatx4 z = floatx4{0.f, 0.f, 0.f, 0.f};
      z = __builtin_amdgcn_mfma_f32_16x16x32_bf16(qf0, kf0, z, 0, 0, 0);
      z = __builtin_amdgcn_mfma_f32_16x16x32_bf16(qf1, kf1, z, 0, 0, 0);
      const float mterm = (1.0f - mk[kt + t * 16 + col]) * -10000.0f;
#pragma unroll
      for (int r = 0; r < 4; r++) sv[t][r] = z[r] * 0.125f + mterm;
    }
    float mnew[4], alpha[4], rs[4];
#pragma unroll
    for (int r = 0; r < 4; r++) {
      float v = fmaxf(fmaxf(sv[0][r], sv[1][r]), fmaxf(sv[2][r], sv[3][r]));
      v = fmaxf(v, __shfl_xor(v, 1));
      v = fmaxf(v, __shfl_xor(v, 2));
      v = fmaxf(v, __shfl_xor(v, 4));
      v = fmaxf(v, __shfl_xor(v, 8));
      mnew[r] = fmaxf(mrun[r], v);
      alpha[r] = __expf(mrun[r] - mnew[r]);
      mrun[r] = mnew[r];
      rs[r] = 0.f;
    }
#pragma unroll
    for (int t = 0; t < 4; t++)
#pragma unroll
      for (int r = 0; r < 4; r++) {
        const float p = __expf(sv[t][r] - mnew[r]);
        sv[t][r] = p;
        rs[r] += p;
      }
#pragma unroll
    for (int r = 0; r < 4; r++) {
      float v = rs[r];
      v += __shfl_xor(v, 1); v += __shfl_xor(v, 2);
      v += __shfl_xor(v, 4); v += __shfl_xor(v, 8);
      lrun[r] = lrun[r] * alpha[r] + v;
    }
#pragma unroll
    for (int d = 0; d < 4; d++)
#pragma unroll
      for (int r = 0; r < 4; r++) acc[d][r] *= alpha[r];

    // C-layout P -> LDS -> A-layout fragments (bf16), per-wave strip
#pragma unroll
    for (int t = 0; t < 4; t++)
#pragma unroll
      for (int r = 0; r < 4; r++)
        P[wave][quad * 4 + r][t * 16 + col] = f2bf(sv[t][r]);

    bf16x8 pf[2];
#pragma unroll
    for (int kk = 0; kk < 2; kk++) {
      const short4v p0 = *(const short4v*)&P[wave][col][kk * 32 + quad * 8];
      const short4v p1 = *(const short4v*)&P[wave][col][kk * 32 + quad * 8 + 4];
      bf16x8 pv;
      pv[0] = p0[0]; pv[1] = p0[1]; pv[2] = p0[2]; pv[3] = p0[3];
      pv[4] = p1[0]; pv[5] = p1[1]; pv[6] = p1[2]; pv[7] = p1[3];
      pf[kk] = pv;
    }
#pragma unroll
    for (int d = 0; d < 4; d++) {
      const short* vp = Vs + (d * 16 + col) * 64;
      const bf16x8 vf0 = *(const bf16x8*)(vp + swz * 8);
      const bf16x8 vf1 = *(const bf16x8*)(vp + (swz ^ 4) * 8);
      acc[d] = __builtin_amdgcn_mfma_f32_16x16x32_bf16(pf[0], vf0, acc[d], 0, 0, 0);
      acc[d] = __builtin_amdgcn_mfma_f32_16x16x32_bf16(pf[1], vf1, acc[d], 0, 0, 0);
    }
  }

#pragma unroll
  for (int r = 0; r < 4; r++) lrun[r] = 1.0f / lrun[r];
#pragma unroll
  for (int d = 0; d < 4; d++)
#pragma unroll
    for (int r = 0; r < 4; r++)
      ctx[((size_t)b * S_ + q0 + quad * 4 + r) * D_ + h * HD_ + d * 16 + col] =
          f2bf(acc[d][r] * lrun[r]);
}

// ---------------- output projection: ctx @ o_w + o_b (fp32 out) ----------------
__global__ __launch_bounds__(256, 2)
void gemm_out(const short* __restrict__ X, const short* __restrict__ WT,
              const float* __restrict__ ob, float* __restrict__ out) {
  __shared__ __align__(16) short As[128 * 32];
  __shared__ __align__(16) short Bs[128 * 32];
  const int tid = threadIdx.x;
  const int wave = tid >> 6, lane = tid & 63;
  const int col = lane & 15, quad = lane >> 4;
  const int m0 = blockIdx.x * 128;
  const int n0 = blockIdx.y * 128;
  const short* Bsrc = WT + (size_t)n0 * D_;
  const int wrow = (wave & 1) * 64;
  const int wcol = (wave >> 1) * 64;

  floatx4 acc[4][4];
#pragma unroll
  for (int i = 0; i < 4; i++)
#pragma unroll
    for (int j = 0; j < 4; j++) acc[i][j] = floatx4{0.f, 0.f, 0.f, 0.f};

  const int srow = tid >> 2;
  const int skcol = (tid & 3) * 8;
  const short* ga = X + (size_t)(m0 + srow) * D_ + skcol;
  const short* gb = Bsrc + (size_t)srow * D_ + skcol;
  short* la = As + tid * 8;
  short* lb = Bs + tid * 8;

  for (int k0 = 0; k0 < D_; k0 += 32) {
    gld_lds16(ga, la);
    gld_lds16(ga + 64 * D_, la + 2048);
    gld_lds16(gb, lb);
    gld_lds16(gb + 64 * D_, lb + 2048);
    ga += 32; gb += 32;
    __syncthreads();
    bf16x8 af[4], bfr[4];
#pragma unroll
    for (int i = 0; i < 4; i++)
      af[i] = *(const bf16x8*)(As + (wrow + i * 16 + col) * 32 + quad * 8);
#pragma unroll
    for (int j = 0; j < 4; j++)
      bfr[j] = *(const bf16x8*)(Bs + (wcol + j * 16 + col) * 32 + quad * 8);
#pragma unroll
    for (int i = 0; i < 4; i++)
#pragma unroll
      for (int j = 0; j < 4; j++)
        acc[i][j] = __builtin_amdgcn_mfma_f32_16x16x32_bf16(af[i], bfr[j],
                                                            acc[i][j], 0, 0, 0);
    __syncthreads();
  }

  float bv[4];
#pragma unroll
  for (int j = 0; j < 4; j++) bv[j] = ob[n0 + wcol + j * 16 + col];

#pragma unroll
  for (int i = 0; i < 4; i++) {
    const int m = m0 + wrow + i * 16 + quad * 4;
#pragma unroll
    for (int j = 0; j < 4; j++) {
      const int n = n0 + wcol + j * 16 + col;
#pragma unroll
      for (int r = 0; r < 4; r++)
        out[(size_t)(m + r) * D_ + n] = acc[i][j][r] + bv[j];
    }
  }
}

extern "C" void kernel_launch(void* const* d_in, const int* in_sizes, int n_in,
                              void* d_out, int out_size, void* d_ws, size_t ws_size,
                              hipStream_t stream) {
  (void)in_sizes; (void)n_in; (void)out_size; (void)ws_size;
  const float* hs  = (const float*)d_in[0];
  const float* msk = (const float*)d_in[1];
  const float* qw  = (const float*)d_in[2];
  const float* qb  = (const float*)d_in[3];
  const float* kw  = (const float*)d_in[4];
  const float* kb  = (const float*)d_in[5];
  const float* vw  = (const float*)d_in[6];
  const float* vb  = (const float*)d_in[7];
  const float* ow  = (const float*)d_in[8];
  const float* ob  = (const float*)d_in[9];
  float* out = (float*)d_out;
  char* ws = (char*)d_ws;

  short* Xb  = (short*)(ws);                    // bf16 hs [4096,1024] (8 MB); reused as Ctx
  short* WT  = (short*)(ws + (8ull  << 20));    // 4 x 1024x1024 bf16 (8 MB)
  short* Qp  = (short*)(ws + (16ull << 20));    // [B,H,S,HD] (8 MB)
  short* Kp  = (short*)(ws + (24ull << 20));    // [B,H,S,HD] (8 MB)
  short* Vtp = (short*)(ws + (32ull << 20));    // [B,H,HD,S] (8 MB)
  short* Ctx = Xb;                              // [B,S,D] bf16 (overlays Xb)

  cvt_hs<<<dim3(4096), 256, 0, stream>>>((const float4*)hs, (short4v*)Xb);
  transpose4<<<dim3(16, 16, 4), 256, 0, stream>>>(qw, kw, vw, ow, WT);
  gemm_qkv<<<dim3(32, 24), 256, 0, stream>>>(Xb, WT, qb, kb, vb, Qp, Kp, Vtp);
  attn<<<dim3(32, 16, 2), 256, 0, stream>>>(Qp, Kp, Vtp, msk, Ctx);
  gemm_out<<<dim3(32, 8), 256, 0, stream>>>(Ctx, WT + 3ull * D_ * D_, ob, out);
}